// Round 4
// baseline (355.611 us; speedup 1.0000x reference)
//
#include <hip/hip_runtime.h>
#include <hip/hip_bf16.h>

#define E_NUM 16
#define HDIM 1024
#define IDIM 1024
#define BM 128
#define BN 32
#define BK 64
#define BKP 72   // LDS row stride in shorts: 144 B = 16*9 -> every row & frag offset 16B-aligned

typedef short bf16x8 __attribute__((ext_vector_type(8)));
typedef short short8 __attribute__((ext_vector_type(8)));
typedef float f32x4 __attribute__((ext_vector_type(4)));

__device__ __forceinline__ short f2bf(float f) {
    return (short)__builtin_bit_cast(unsigned short, __float2bfloat16(f));
}

// ---------------- routing: bucket token ids by expert ----------------
__global__ void route_kernel(const int* __restrict__ eidx, int n_tok,
                             int* __restrict__ counts, int* __restrict__ tlist) {
    __shared__ int sc[E_NUM];
    int t = threadIdx.x;
    if (t < E_NUM) sc[t] = 0;
    __syncthreads();
    for (int n = t; n < n_tok; n += blockDim.x) {
        int e = eidx[n];
        if (e >= 0 && e < E_NUM) {
            int p = atomicAdd(&sc[e], 1);
            tlist[e * n_tok + p] = n;
        }
    }
    __syncthreads();
    if (t < E_NUM) counts[t] = sc[t];
}

// ---------------- phase 1: gate/up GEMMs + silu*mul -> inter (bf16) ----------------
__global__ __launch_bounds__(256) void gateup_kernel(
    const float* __restrict__ x, const float* __restrict__ Wg,
    const float* __restrict__ Wu, const int* __restrict__ counts,
    const int* __restrict__ tlist, unsigned short* __restrict__ inter, int n_tok)
{
    const int NT = IDIM / BN;                 // 32
    const int MT = (n_tok + BM - 1) / BM;     // 16
    int bid = blockIdx.x;
    int e = bid / (MT * NT);
    int rem = bid - e * (MT * NT);
    int mt = rem / NT;
    int nt = rem - mt * NT;
    int cnt = counts[e];
    if (cnt < 0) cnt = 0;
    if (cnt > n_tok) cnt = n_tok;
    int row0 = mt * BM;
    if (row0 >= cnt) return;
    int rows = cnt - row0; if (rows > BM) rows = BM;
    int n0 = nt * BN;

    __shared__ __align__(16) unsigned short As[BM][BKP];
    __shared__ __align__(16) unsigned short Bg[BN][BKP];
    __shared__ __align__(16) unsigned short Bu[BN][BKP];
    __shared__ int tok[BM];

    int t = threadIdx.x;
    for (int i = t; i < BM; i += 256)
        tok[i] = (i < rows) ? tlist[e * n_tok + row0 + i] : -1;
    __syncthreads();

    // ---- staging coords ----
    // A: 2 threads per row; each covers 32 fp32 (8 float4)
    int ar = t >> 1;
    int ac = (t & 1) * 32;
    int atok = tok[ar];
    const float* aptr = x + (size_t)(atok < 0 ? 0 : atok) * HDIM + ac;
    // B: thread t handles column n = t&31, k-chunk (t>>5)*8 (8 k's, coalesced per k-slice)
    int bn = t & 31;
    int bk0 = (t >> 5) * 8;
    const float* wg_b = Wg + (size_t)e * HDIM * IDIM + n0 + bn;
    const float* wu_b = Wu + (size_t)e * HDIM * IDIM + n0 + bn;

    float4 Areg[8];
    float Greg[8], Ureg[8];

    auto load_tile = [&](int k0) {
        #pragma unroll
        for (int i = 0; i < 8; ++i) {
            float4 v = make_float4(0.f, 0.f, 0.f, 0.f);
            if (atok >= 0) v = *(const float4*)(aptr + k0 + 4 * i);
            Areg[i] = v;
        }
        #pragma unroll
        for (int i = 0; i < 8; ++i) {
            size_t o = (size_t)(k0 + bk0 + i) * IDIM;
            Greg[i] = wg_b[o];
            Ureg[i] = wu_b[o];
        }
    };
    auto store_tile = [&]() {
        #pragma unroll
        for (int i = 0; i < 8; i += 2) {
            short8 s;
            s[0] = f2bf(Areg[i].x);     s[1] = f2bf(Areg[i].y);
            s[2] = f2bf(Areg[i].z);     s[3] = f2bf(Areg[i].w);
            s[4] = f2bf(Areg[i + 1].x); s[5] = f2bf(Areg[i + 1].y);
            s[6] = f2bf(Areg[i + 1].z); s[7] = f2bf(Areg[i + 1].w);
            *(short8*)&As[ar][ac + 4 * i] = s;
        }
        #pragma unroll
        for (int i = 0; i < 8; i += 4) {
            ushort4 g, u;
            g.x = f2bf(Greg[i]); g.y = f2bf(Greg[i + 1]); g.z = f2bf(Greg[i + 2]); g.w = f2bf(Greg[i + 3]);
            u.x = f2bf(Ureg[i]); u.y = f2bf(Ureg[i + 1]); u.z = f2bf(Ureg[i + 2]); u.w = f2bf(Ureg[i + 3]);
            *(ushort4*)&Bg[bn][bk0 + i] = g;
            *(ushort4*)&Bu[bn][bk0 + i] = u;
        }
    };

    int wid = t >> 6, lane = t & 63;
    int wm = wid >> 1, wn = wid & 1;
    int lr = lane & 15, lk = lane >> 4, lk8 = (lane >> 4) * 8;

    f32x4 accg[4] = {};
    f32x4 accu[4] = {};

    load_tile(0);
    const int NKT = HDIM / BK;  // 16
    for (int kt = 0; kt < NKT; ++kt) {
        store_tile();
        __syncthreads();
        if (kt + 1 < NKT) load_tile((kt + 1) * BK);
        #pragma unroll
        for (int ks = 0; ks < 2; ++ks) {
            bf16x8 bg = *(const bf16x8*)&Bg[wn * 16 + lr][ks * 32 + lk8];
            bf16x8 bu = *(const bf16x8*)&Bu[wn * 16 + lr][ks * 32 + lk8];
            #pragma unroll
            for (int fm = 0; fm < 4; ++fm) {
                bf16x8 a = *(const bf16x8*)&As[wm * 64 + fm * 16 + lr][ks * 32 + lk8];
                accg[fm] = __builtin_amdgcn_mfma_f32_16x16x32_bf16(a, bg, accg[fm], 0, 0, 0);
                accu[fm] = __builtin_amdgcn_mfma_f32_16x16x32_bf16(a, bu, accu[fm], 0, 0, 0);
            }
        }
        __syncthreads();
    }

    // epilogue: silu(g)*u -> bf16 inter[token][col]
    #pragma unroll
    for (int fm = 0; fm < 4; ++fm) {
        #pragma unroll
        for (int rr = 0; rr < 4; ++rr) {
            int row = wm * 64 + fm * 16 + lk * 4 + rr;
            if (row < rows) {
                int tk = tok[row];
                if (tk >= 0 && tk < n_tok) {
                    float g = accg[fm][rr];
                    float u = accu[fm][rr];
                    float s = g / (1.0f + __expf(-g)) * u;
                    inter[(size_t)tk * IDIM + n0 + wn * 16 + lr] = (unsigned short)f2bf(s);
                }
            }
        }
    }
}

// ---------------- phase 2: out = inter @ down^T (contract contiguous axis) ----------------
__global__ __launch_bounds__(256) void down_kernel(
    const unsigned short* __restrict__ inter, const float* __restrict__ Wd,
    const int* __restrict__ counts, const int* __restrict__ tlist,
    float* __restrict__ out, int n_tok)
{
    const int NT = HDIM / BN;                 // 32
    const int MT = (n_tok + BM - 1) / BM;     // 16
    int bid = blockIdx.x;
    int e = bid / (MT * NT);
    int rem = bid - e * (MT * NT);
    int mt = rem / NT;
    int nt = rem - mt * NT;
    int cnt = counts[e];
    if (cnt < 0) cnt = 0;
    if (cnt > n_tok) cnt = n_tok;
    int row0 = mt * BM;
    if (row0 >= cnt) return;
    int rows = cnt - row0; if (rows > BM) rows = BM;
    int j0 = nt * BN;

    __shared__ __align__(16) unsigned short As[BM][BKP];
    __shared__ __align__(16) unsigned short Bs[BN][BKP];
    __shared__ int tok[BM];

    int t = threadIdx.x;
    for (int i = t; i < BM; i += 256)
        tok[i] = (i < rows) ? tlist[e * n_tok + row0 + i] : -1;
    __syncthreads();

    // A: 2 threads per row; 32 bf16 (4 uint4) each — no conversion needed
    int ar = t >> 1;
    int ac = (t & 1) * 32;
    int atok = tok[ar];
    const unsigned short* aptr = inter + (size_t)(atok < 0 ? 0 : atok) * IDIM + ac;
    // B: 8 threads per row j; 8 fp32 each, contiguous in k
    int bj = t >> 3;
    int bco = (t & 7) * 8;
    const float* wd_b = Wd + (size_t)e * IDIM * HDIM + (size_t)(j0 + bj) * HDIM + bco;

    uint4 Areg[4];
    float Dreg[8];

    auto load_tile = [&](int k0) {
        #pragma unroll
        for (int i = 0; i < 4; ++i) {
            uint4 v = make_uint4(0u, 0u, 0u, 0u);
            if (atok >= 0) v = *(const uint4*)(aptr + k0 + 8 * i);
            Areg[i] = v;
        }
        #pragma unroll
        for (int i = 0; i < 8; i += 4) {
            float4 w = *(const float4*)(wd_b + k0 + i);
            Dreg[i] = w.x; Dreg[i + 1] = w.y; Dreg[i + 2] = w.z; Dreg[i + 3] = w.w;
        }
    };
    auto store_tile = [&]() {
        #pragma unroll
        for (int i = 0; i < 4; ++i)
            *(uint4*)&As[ar][ac + 8 * i] = Areg[i];
        short8 s;
        #pragma unroll
        for (int i = 0; i < 8; ++i) s[i] = f2bf(Dreg[i]);
        *(short8*)&Bs[bj][bco] = s;
    };

    int wid = t >> 6, lane = t & 63;
    int wm = wid >> 1, wn = wid & 1;
    int lr = lane & 15, lk = lane >> 4, lk8 = (lane >> 4) * 8;

    f32x4 acc[4] = {};

    load_tile(0);
    const int NKT = IDIM / BK;  // 16
    for (int kt = 0; kt < NKT; ++kt) {
        store_tile();
        __syncthreads();
        if (kt + 1 < NKT) load_tile((kt + 1) * BK);
        #pragma unroll
        for (int ks = 0; ks < 2; ++ks) {
            bf16x8 bv = *(const bf16x8*)&Bs[wn * 16 + lr][ks * 32 + lk8];
            #pragma unroll
            for (int fm = 0; fm < 4; ++fm) {
                bf16x8 a = *(const bf16x8*)&As[wm * 64 + fm * 16 + lr][ks * 32 + lk8];
                acc[fm] = __builtin_amdgcn_mfma_f32_16x16x32_bf16(a, bv, acc[fm], 0, 0, 0);
            }
        }
        __syncthreads();
    }

    #pragma unroll
    for (int fm = 0; fm < 4; ++fm) {
        #pragma unroll
        for (int rr = 0; rr < 4; ++rr) {
            int row = wm * 64 + fm * 16 + lk * 4 + rr;
            if (row < rows) {
                int tk = tok[row];
                if (tk >= 0 && tk < n_tok)
                    out[(size_t)tk * HDIM + j0 + wn * 16 + lr] = acc[fm][rr];
            }
        }
    }
}

extern "C" void kernel_launch(void* const* d_in, const int* in_sizes, int n_in,
                              void* d_out, int out_size, void* d_ws, size_t ws_size,
                              hipStream_t stream) {
    const float* x  = (const float*)d_in[0];
    const int* eidx = (const int*)d_in[1];
    const float* Wg = (const float*)d_in[2];
    const float* Wu = (const float*)d_in[3];
    const float* Wd = (const float*)d_in[4];
    float* out = (float*)d_out;
    int n_tok = in_sizes[1];   // B*S = 2048

    char* ws = (char*)d_ws;
    int* counts           = (int*)ws;                            // E ints
    int* tlist            = (int*)(ws + 1024);                   // E * n_tok ints (128 KB)
    unsigned short* inter = (unsigned short*)(ws + (1 << 18));   // n_tok * IDIM bf16 (4 MB)

    route_kernel<<<1, 256, 0, stream>>>(eidx, n_tok, counts, tlist);
    int MT = (n_tok + BM - 1) / BM;
    gateup_kernel<<<E_NUM * MT * (IDIM / BN), 256, 0, stream>>>(x, Wg, Wu, counts, tlist, inter, n_tok);
    down_kernel<<<E_NUM * MT * (HDIM / BN), 256, 0, stream>>>(inter, Wd, counts, tlist, out, n_tok);
}

// Round 5
// 325.819 us; speedup vs baseline: 1.0914x; 1.0914x over previous
//
#include <hip/hip_runtime.h>
#include <hip/hip_bf16.h>

#define E_NUM 16
#define HDIM 1024
#define IDIM 1024
#define BM 128
#define BN 64
#define BK 32
#define NT 16            // IDIM/BN
#define NKT 32           // HDIM/BK
#define MT_MAX 4
#define AKP 40           // gateup A LDS row stride in shorts (80 B)

typedef short bf16x8 __attribute__((ext_vector_type(8)));
typedef short short8v __attribute__((ext_vector_type(8)));
typedef float f32x4 __attribute__((ext_vector_type(4)));

__device__ __forceinline__ unsigned short f2bf(float f) {
    return __builtin_bit_cast(unsigned short, __float2bfloat16(f));
}

// 16B-per-lane async global->LDS: l must be WAVE-UNIFORM; HW writes lane's 16B at l + lane*16.
// g is PER-LANE.
__device__ __forceinline__ void gll16(const unsigned short* g, unsigned short* l) {
#if __has_builtin(__builtin_amdgcn_global_load_lds)
    __builtin_amdgcn_global_load_lds((const __attribute__((address_space(1))) unsigned int*)g,
                                     (__attribute__((address_space(3))) unsigned int*)l, 16, 0, 0);
#else
    *(uint4*)(l + (threadIdx.x & 63) * 8) = *(const uint4*)g;
#endif
}

// ---------------- routing ----------------
__global__ void route_kernel(const int* __restrict__ eidx, int n_tok,
                             int* __restrict__ counts, int* __restrict__ tlist) {
    __shared__ int sc[E_NUM];
    int t = threadIdx.x;
    if (t < E_NUM) sc[t] = 0;
    __syncthreads();
    for (int n = t; n < n_tok; n += blockDim.x) {
        int e = eidx[n];
        if (e >= 0 && e < E_NUM) {
            int p = atomicAdd(&sc[e], 1);
            tlist[e * n_tok + p] = n;
        }
    }
    __syncthreads();
    if (t < E_NUM) counts[t] = sc[t];
}

// ---------------- pack gate/up: fp32 [k][i] -> bf16 tiles [e][mat][nt][kt][64n][32k] ----------------
__global__ __launch_bounds__(256) void pack_gu_kernel(const float* __restrict__ Wg,
                                                      const float* __restrict__ Wu,
                                                      unsigned short* __restrict__ gu) {
    int bid = blockIdx.x;                    // 16e * 2mat * 32kg
    int e = bid >> 6, mat = (bid >> 5) & 1, kg = bid & 31;
    const float* src = (mat ? Wu : Wg) + (size_t)e * HDIM * IDIM + (size_t)kg * BK * IDIM;
    unsigned short* dstb = gu + ((size_t)((e * 2 + mat) * NT * NKT + kg)) * 2048; // tile(nt)= +nt*NKT*2048

    __shared__ unsigned short Ls[4][1032];
    int t = threadIdx.x;
    uint2 g8[4][8];

    #pragma unroll
    for (int s = 0; s < 8; ++s) {
        float4 v[4];
        #pragma unroll
        for (int g = 0; g < 4; ++g)
            v[g] = *(const float4*)(src + (size_t)(s * 4 + g) * IDIM + t * 4);
        if (s) __syncthreads();
        #pragma unroll
        for (int g = 0; g < 4; ++g) {
            ushort4 b;
            b.x = f2bf(v[g].x); b.y = f2bf(v[g].y); b.z = f2bf(v[g].z); b.w = f2bf(v[g].w);
            *(ushort4*)&Ls[g][t * 4] = b;
        }
        __syncthreads();
        #pragma unroll
        for (int q = 0; q < 4; ++q) {
            int n = t + 256 * q;
            unsigned a0 = Ls[0][n], a1 = Ls[1][n], a2 = Ls[2][n], a3 = Ls[3][n];
            uint2 r; r.x = a0 | (a1 << 16); r.y = a2 | (a3 << 16);
            g8[q][s] = r;
        }
    }
    #pragma unroll
    for (int q = 0; q < 4; ++q) {
        int n = t + 256 * q;
        unsigned short* tile = dstb + (size_t)(n >> 6) * NKT * 2048 + (n & 63) * 32;
        #pragma unroll
        for (int c = 0; c < 4; ++c) {
            uint4 w = make_uint4(g8[q][2 * c].x, g8[q][2 * c].y, g8[q][2 * c + 1].x, g8[q][2 * c + 1].y);
            *(uint4*)(tile + c * 8) = w;
        }
    }
}

// ---------------- pack down: fp32 [j][k] (k contiguous) -> bf16 tiles [e][jt][kt][64j][32k] ----------------
__global__ __launch_bounds__(256) void pack_d_kernel(const float* __restrict__ Wd,
                                                     unsigned short* __restrict__ dp) {
    int bid = blockIdx.x;                    // 16e * 16jt * 4js
    int e = bid >> 6, jt = (bid >> 2) & 15, js = bid & 3;
    const float* src = Wd + (size_t)e * IDIM * HDIM + (size_t)(jt * 64 + js * 16) * HDIM;
    unsigned short* tb = dp + ((size_t)(e * NT + jt) * NKT) * 2048;
    int t = threadIdx.x;
    int k = t * 4;
    #pragma unroll 4
    for (int i = 0; i < 16; ++i) {
        int jl = js * 16 + i;
        float4 v = *(const float4*)(src + (size_t)i * HDIM + k);
        ushort4 b;
        b.x = f2bf(v.x); b.y = f2bf(v.y); b.z = f2bf(v.z); b.w = f2bf(v.w);
        *(ushort4*)(tb + (size_t)(k >> 5) * 2048 + jl * 32 + (k & 31)) = b;
    }
}

// ---------------- phase 1: gate/up GEMMs + silu*mul -> inter (bf16) ----------------
template<int PACKED>
__global__ __launch_bounds__(256) void gateup_kernel(
    const float* __restrict__ x, const float* __restrict__ Wg, const float* __restrict__ Wu,
    const unsigned short* __restrict__ gu, const int* __restrict__ counts,
    const int* __restrict__ tlist, unsigned short* __restrict__ inter, int n_tok)
{
    int bid = blockIdx.x;
    int e = bid / (MT_MAX * NT);
    int rem = bid % (MT_MAX * NT);
    int mt = rem / NT, nt = rem % NT;
    int cnt = counts[e];
    if (cnt < 0) cnt = 0;
    if (cnt > n_tok) cnt = n_tok;
    int row0 = mt * BM;
    if (row0 >= cnt) return;
    int rows = cnt - row0; if (rows > BM) rows = BM;
    int n0 = nt * BN;

    __shared__ __align__(16) unsigned short As[2][BM][AKP];
    __shared__ __align__(16) unsigned short Bs[2][2][BN * BK];
    __shared__ int tok[BM];

    int t = threadIdx.x;
    for (int i = t; i < BM; i += 256) {
        int tk = (i < rows) ? tlist[e * n_tok + row0 + i] : -1;
        tok[i] = (tk >= 0 && tk < n_tok) ? tk : -1;
    }
    __syncthreads();

    int wid = t >> 6, lane = t & 63;
    int ar = t >> 1, ah = (t & 1) * 16;
    int atok = tok[ar];
    const float* aptr = x + (size_t)(atok < 0 ? 0 : atok) * HDIM + ah;

    // direct-mode B coords
    int bk1 = t >> 4, bf = (t & 15) * 4;
    const float* wg_b = Wg + (size_t)e * HDIM * IDIM + n0;
    const float* wu_b = Wu + (size_t)e * HDIM * IDIM + n0;
    // packed-mode B base (mat 0); mat1 = +NT*NKT*2048 shorts
    const unsigned short* gub = gu + ((size_t)((e * 2) * NT + nt) * NKT) * 2048;

    float4 Ar[4];
    float4 Bgr[2], Bur[2];

    auto loadA = [&](int kt) {
        #pragma unroll
        for (int i = 0; i < 4; ++i)
            Ar[i] = *(const float4*)(aptr + kt * BK + 4 * i);
    };
    auto storeA = [&](int buf) {
        short8v s0, s1;
        s0[0] = f2bf(Ar[0].x); s0[1] = f2bf(Ar[0].y); s0[2] = f2bf(Ar[0].z); s0[3] = f2bf(Ar[0].w);
        s0[4] = f2bf(Ar[1].x); s0[5] = f2bf(Ar[1].y); s0[6] = f2bf(Ar[1].z); s0[7] = f2bf(Ar[1].w);
        s1[0] = f2bf(Ar[2].x); s1[1] = f2bf(Ar[2].y); s1[2] = f2bf(Ar[2].z); s1[3] = f2bf(Ar[2].w);
        s1[4] = f2bf(Ar[3].x); s1[5] = f2bf(Ar[3].y); s1[6] = f2bf(Ar[3].z); s1[7] = f2bf(Ar[3].w);
        *(short8v*)&As[buf][ar][ah] = s0;
        *(short8v*)&As[buf][ar][ah + 8] = s1;
    };
    auto stageB_gll = [&](int kt, int buf) {
        int mat = wid >> 1, half = wid & 1;
        const unsigned short* tsrc = gub + (size_t)mat * NT * NKT * 2048 + (size_t)kt * 2048;
        #pragma unroll
        for (int i = 0; i < 2; ++i)
            gll16(tsrc + half * 1024 + i * 512 + lane * 8,
                  &Bs[buf][mat][half * 1024 + i * 512]);
    };
    auto loadB_dir = [&](int kt) {
        int k0 = kt * BK;
        Bgr[0] = *(const float4*)(wg_b + (size_t)(k0 + bk1) * IDIM + bf);
        Bgr[1] = *(const float4*)(wg_b + (size_t)(k0 + 16 + bk1) * IDIM + bf);
        Bur[0] = *(const float4*)(wu_b + (size_t)(k0 + bk1) * IDIM + bf);
        Bur[1] = *(const float4*)(wu_b + (size_t)(k0 + 16 + bk1) * IDIM + bf);
    };
    auto storeB_dir = [&](int buf) {
        #pragma unroll
        for (int p = 0; p < 2; ++p) {
            int k = p * 16 + bk1;
            Bs[buf][0][(bf + 0) * 32 + k] = f2bf(Bgr[p].x);
            Bs[buf][0][(bf + 1) * 32 + k] = f2bf(Bgr[p].y);
            Bs[buf][0][(bf + 2) * 32 + k] = f2bf(Bgr[p].z);
            Bs[buf][0][(bf + 3) * 32 + k] = f2bf(Bgr[p].w);
            Bs[buf][1][(bf + 0) * 32 + k] = f2bf(Bur[p].x);
            Bs[buf][1][(bf + 1) * 32 + k] = f2bf(Bur[p].y);
            Bs[buf][1][(bf + 2) * 32 + k] = f2bf(Bur[p].z);
            Bs[buf][1][(bf + 3) * 32 + k] = f2bf(Bur[p].w);
        }
    };

    int wm = wid >> 1, wn = wid & 1;
    int lr = lane & 15, lk = lane >> 4, lk8 = (lane >> 4) * 8;
    f32x4 accg[4][2] = {};
    f32x4 accu[4][2] = {};

    if (PACKED) stageB_gll(0, 0); else loadB_dir(0);
    loadA(0);
    if (!PACKED) storeB_dir(0);
    storeA(0);
    __syncthreads();

    for (int kt = 0; kt < NKT; ++kt) {
        int cur = kt & 1, nxt = cur ^ 1;
        if (kt + 1 < NKT) {
            if (PACKED) stageB_gll(kt + 1, nxt); else loadB_dir(kt + 1);
            loadA(kt + 1);
        }
        // MFMA on cur
        {
            bf16x8 a[4];
            #pragma unroll
            for (int fm = 0; fm < 4; ++fm)
                a[fm] = *(const bf16x8*)&As[cur][wm * 64 + fm * 16 + lr][lk8];
            #pragma unroll
            for (int fn = 0; fn < 2; ++fn) {
                int n = wn * 32 + fn * 16 + lr;
                bf16x8 bg = *(const bf16x8*)&Bs[cur][0][n * 32 + lk8];
                bf16x8 bu = *(const bf16x8*)&Bs[cur][1][n * 32 + lk8];
                #pragma unroll
                for (int fm = 0; fm < 4; ++fm) {
                    accg[fm][fn] = __builtin_amdgcn_mfma_f32_16x16x32_bf16(a[fm], bg, accg[fm][fn], 0, 0, 0);
                    accu[fm][fn] = __builtin_amdgcn_mfma_f32_16x16x32_bf16(a[fm], bu, accu[fm][fn], 0, 0, 0);
                }
            }
        }
        if (kt + 1 < NKT) {
            storeA(nxt);
            if (!PACKED) storeB_dir(nxt);
        }
        __syncthreads();
    }

    #pragma unroll
    for (int fm = 0; fm < 4; ++fm) {
        #pragma unroll
        for (int rr = 0; rr < 4; ++rr) {
            int row = wm * 64 + fm * 16 + lk * 4 + rr;
            if (row < rows) {
                int tk = tok[row];
                if (tk >= 0) {
                    #pragma unroll
                    for (int fn = 0; fn < 2; ++fn) {
                        float g = accg[fm][fn][rr];
                        float u = accu[fm][fn][rr];
                        float s = g / (1.0f + __expf(-g)) * u;
                        inter[(size_t)tk * IDIM + n0 + wn * 32 + fn * 16 + lr] = f2bf(s);
                    }
                }
            }
        }
    }
}

// ---------------- phase 2: out = inter @ down^T ----------------
template<int PACKED>
__global__ __launch_bounds__(256) void down_kernel(
    const unsigned short* __restrict__ inter, const float* __restrict__ Wd,
    const unsigned short* __restrict__ dp, const int* __restrict__ counts,
    const int* __restrict__ tlist, float* __restrict__ out, int n_tok)
{
    int bid = blockIdx.x;
    int e = bid / (MT_MAX * NT);
    int rem = bid % (MT_MAX * NT);
    int mt = rem / NT, jt = rem % NT;
    int cnt = counts[e];
    if (cnt < 0) cnt = 0;
    if (cnt > n_tok) cnt = n_tok;
    int row0 = mt * BM;
    if (row0 >= cnt) return;
    int rows = cnt - row0; if (rows > BM) rows = BM;
    int j0 = jt * BN;

    __shared__ __align__(16) unsigned short As[2][BM * BK];   // [row*32+k], 64B rows, linear for gll
    __shared__ __align__(16) unsigned short Bs[2][BN * BK];
    __shared__ int tok[BM];

    int t = threadIdx.x;
    for (int i = t; i < BM; i += 256) {
        int tk = (i < rows) ? tlist[e * n_tok + row0 + i] : -1;
        tok[i] = (tk >= 0 && tk < n_tok) ? tk : -1;
    }
    __syncthreads();

    int wid = t >> 6, lane = t & 63;
    const unsigned short* dtile = dp + ((size_t)(e * NT + jt) * NKT) * 2048;

    // direct-mode B coords
    int bj = t >> 2, bq = (t & 3) * 8;
    const float* wdb = Wd + (size_t)e * IDIM * HDIM + (size_t)(j0 + bj) * HDIM + bq;
    float4 Bdr[2];

    auto stageA = [&](int kt, int buf) {
        #pragma unroll
        for (int i = 0; i < 2; ++i) {
            int row = wid * 32 + i * 16 + (lane >> 2);
            int tk = tok[row]; if (tk < 0) tk = 0;
            const unsigned short* g = inter + (size_t)tk * IDIM + kt * BK + (lane & 3) * 8;
            gll16(g, &As[buf][(wid * 32 + i * 16) * 32]);
        }
    };
    auto stageB_gll = [&](int kt, int buf) {
        gll16(dtile + (size_t)kt * 2048 + wid * 512 + lane * 8, &Bs[buf][wid * 512]);
    };
    auto loadB_dir = [&](int kt) {
        Bdr[0] = *(const float4*)(wdb + kt * BK);
        Bdr[1] = *(const float4*)(wdb + kt * BK + 4);
    };
    auto storeB_dir = [&](int buf) {
        ushort4 b0, b1;
        b0.x = f2bf(Bdr[0].x); b0.y = f2bf(Bdr[0].y); b0.z = f2bf(Bdr[0].z); b0.w = f2bf(Bdr[0].w);
        b1.x = f2bf(Bdr[1].x); b1.y = f2bf(Bdr[1].y); b1.z = f2bf(Bdr[1].z); b1.w = f2bf(Bdr[1].w);
        *(ushort4*)&Bs[buf][bj * 32 + bq] = b0;
        *(ushort4*)&Bs[buf][bj * 32 + bq + 4] = b1;
    };

    int wm = wid >> 1, wn = wid & 1;
    int lr = lane & 15, lk = lane >> 4, lk8 = (lane >> 4) * 8;
    f32x4 acc[4][2] = {};

    stageA(0, 0);
    if (PACKED) stageB_gll(0, 0); else { loadB_dir(0); storeB_dir(0); }
    __syncthreads();

    for (int kt = 0; kt < NKT; ++kt) {
        int cur = kt & 1, nxt = cur ^ 1;
        if (kt + 1 < NKT) {
            stageA(kt + 1, nxt);
            if (PACKED) stageB_gll(kt + 1, nxt); else loadB_dir(kt + 1);
        }
        {
            bf16x8 a[4];
            #pragma unroll
            for (int fm = 0; fm < 4; ++fm)
                a[fm] = *(const bf16x8*)&As[cur][(wm * 64 + fm * 16 + lr) * 32 + lk8];
            #pragma unroll
            for (int fn = 0; fn < 2; ++fn) {
                bf16x8 bv = *(const bf16x8*)&Bs[cur][(wn * 32 + fn * 16 + lr) * 32 + lk8];
                #pragma unroll
                for (int fm = 0; fm < 4; ++fm)
                    acc[fm][fn] = __builtin_amdgcn_mfma_f32_16x16x32_bf16(a[fm], bv, acc[fm][fn], 0, 0, 0);
            }
        }
        if (kt + 1 < NKT) {
            if (!PACKED) storeB_dir(nxt);
        }
        __syncthreads();
    }

    #pragma unroll
    for (int fm = 0; fm < 4; ++fm) {
        #pragma unroll
        for (int rr = 0; rr < 4; ++rr) {
            int row = wm * 64 + fm * 16 + lk * 4 + rr;
            if (row < rows) {
                int tk = tok[row];
                if (tk >= 0) {
                    #pragma unroll
                    for (int fn = 0; fn < 2; ++fn)
                        out[(size_t)tk * HDIM + j0 + wn * 32 + fn * 16 + lr] = acc[fm][fn][rr];
                }
            }
        }
    }
}

extern "C" void kernel_launch(void* const* d_in, const int* in_sizes, int n_in,
                              void* d_out, int out_size, void* d_ws, size_t ws_size,
                              hipStream_t stream) {
    const float* x  = (const float*)d_in[0];
    const int* eidx = (const int*)d_in[1];
    const float* Wg = (const float*)d_in[2];
    const float* Wu = (const float*)d_in[3];
    const float* Wd = (const float*)d_in[4];
    float* out = (float*)d_out;
    int n_tok = in_sizes[1];   // B*S = 2048

    char* ws = (char*)d_ws;
    size_t off_tlist = 1024;
    size_t off_inter = (size_t)1 << 18;                              // 256 KB
    size_t off_gu    = off_inter + (size_t)n_tok * IDIM * 2;         // + 4 MB
    size_t sz_gu     = (size_t)E_NUM * 2 * NT * NKT * 4096;          // 64 MB
    size_t off_d     = off_gu + sz_gu;
    size_t sz_d      = (size_t)E_NUM * NT * NKT * 4096;              // 32 MB

    int* counts           = (int*)ws;
    int* tlist            = (int*)(ws + off_tlist);
    unsigned short* inter = (unsigned short*)(ws + off_inter);
    unsigned short* gu    = (unsigned short*)(ws + off_gu);
    unsigned short* dpk   = (unsigned short*)(ws + off_d);

    bool packGU = ws_size >= off_d;
    bool packD  = ws_size >= off_d + sz_d;

    route_kernel<<<1, 256, 0, stream>>>(eidx, n_tok, counts, tlist);
    if (packGU) pack_gu_kernel<<<E_NUM * 2 * NKT, 256, 0, stream>>>(Wg, Wu, gu);
    if (packD)  pack_d_kernel<<<E_NUM * NT * 4, 256, 0, stream>>>(Wd, dpk);

    int grid = E_NUM * MT_MAX * NT;
    if (packGU)
        gateup_kernel<1><<<grid, 256, 0, stream>>>(x, Wg, Wu, gu, counts, tlist, inter, n_tok);
    else
        gateup_kernel<0><<<grid, 256, 0, stream>>>(x, Wg, Wu, gu, counts, tlist, inter, n_tok);
    if (packD)
        down_kernel<1><<<grid, 256, 0, stream>>>(inter, Wd, dpk, counts, tlist, out, n_tok);
    else
        down_kernel<0><<<grid, 256, 0, stream>>>(inter, Wd, dpk, counts, tlist, out, n_tok);
}

// Round 7
// 301.196 us; speedup vs baseline: 1.1807x; 1.0817x over previous
//
#include <hip/hip_runtime.h>
#include <hip/hip_bf16.h>

#define E_NUM 16
#define HDIM 1024
#define IDIM 1024
#define BM 128
#define BN 32
#define BK 32
#define NT 32            // IDIM/BN (and HDIM/BN for down)
#define NKT 32           // K / BK
#define MT_MAX 4
#define AKP 40           // padded LDS row stride (80 B) -> conflict-free b128 frag reads

typedef short bf16x8 __attribute__((ext_vector_type(8)));
typedef short short8v __attribute__((ext_vector_type(8)));
typedef float f32x4 __attribute__((ext_vector_type(4)));

__device__ __forceinline__ unsigned short f2bf(float f) {
    return __builtin_bit_cast(unsigned short, __float2bfloat16(f));
}

// async global->LDS, 16B per lane: LDS base must be wave-uniform; HW writes lane's 16B at l + lane*16.
__device__ __forceinline__ void gll16(const unsigned short* g, unsigned short* l) {
#if __has_builtin(__builtin_amdgcn_global_load_lds)
    __builtin_amdgcn_global_load_lds((const __attribute__((address_space(1))) unsigned int*)g,
                                     (__attribute__((address_space(3))) unsigned int*)l, 16, 0, 0);
#else
    *(uint4*)(l + (threadIdx.x & 63) * 8) = *(const uint4*)g;
#endif
}

// ---------------- routing ----------------
__global__ void route_kernel(const int* __restrict__ eidx, int n_tok,
                             int* __restrict__ counts, int* __restrict__ tlist) {
    __shared__ int sc[E_NUM];
    int t = threadIdx.x;
    if (t < E_NUM) sc[t] = 0;
    __syncthreads();
    for (int n = t; n < n_tok; n += blockDim.x) {
        int e = eidx[n];
        if (e >= 0 && e < E_NUM) {
            int p = atomicAdd(&sc[e], 1);
            tlist[e * n_tok + p] = n;
        }
    }
    __syncthreads();
    if (t < E_NUM) counts[t] = sc[t];
}

// ---- pack gate/up: fp32 [k][i] -> bf16 swizzled tiles [e][mat][nt][kt][(n*32+k8)^((n&7)<<3)] ----
// Barrier-free: each thread does a 4i x 8k register transpose.
__global__ __launch_bounds__(256) void pack_gu_kernel(const float* __restrict__ Wg,
                                                      const float* __restrict__ Wu,
                                                      unsigned short* __restrict__ gu) {
    int bid = blockIdx.x;                       // 16e * 2mat * 32kg * 4ih = 4096
    int e = bid >> 8, mat = (bid >> 7) & 1, kg = (bid >> 2) & 31, ih = bid & 3;
    int t = threadIdx.x;
    int l = t & 63, wq = t >> 6;
    const float* src = (mat ? Wu : Wg) + (size_t)e * HDIM * IDIM
                     + (size_t)(kg * 32 + wq * 8) * IDIM + ih * 256 + l * 4;
    f32x4 v[8];
    #pragma unroll
    for (int j = 0; j < 8; ++j)
        v[j] = *(const f32x4*)(src + (size_t)j * IDIM);

    int nt = ih * 8 + (l >> 3);
    size_t tb = ((size_t)((e * 2 + mat) * NT + nt) * NKT + kg) * 1024;
    #pragma unroll
    for (int c = 0; c < 4; ++c) {
        int nn = (l & 7) * 4 + c;
        unsigned w0 = (unsigned)f2bf(v[0][c]) | ((unsigned)f2bf(v[1][c]) << 16);
        unsigned w1 = (unsigned)f2bf(v[2][c]) | ((unsigned)f2bf(v[3][c]) << 16);
        unsigned w2 = (unsigned)f2bf(v[4][c]) | ((unsigned)f2bf(v[5][c]) << 16);
        unsigned w3 = (unsigned)f2bf(v[6][c]) | ((unsigned)f2bf(v[7][c]) << 16);
        int idx = (nn * 32 + wq * 8) ^ ((nn & 7) << 3);   // pre-applied read swizzle
        *(uint4*)(gu + tb + idx) = make_uint4(w0, w1, w2, w3);
    }
}

// ---------------- phase 1: gate/up GEMMs + silu*mul -> inter (bf16) ----------------
template<int PACKED>
__global__ __launch_bounds__(512) void gateup_kernel(
    const float* __restrict__ x, const float* __restrict__ Wg, const float* __restrict__ Wu,
    const unsigned short* __restrict__ gu, const int* __restrict__ counts,
    const int* __restrict__ tlist, unsigned short* __restrict__ inter, int n_tok)
{
    int bid = blockIdx.x;
    int e = bid / (MT_MAX * NT);
    int rem = bid % (MT_MAX * NT);
    int mt = rem / NT, nt = rem % NT;
    int cnt = counts[e];
    if (cnt < 0) cnt = 0;
    if (cnt > n_tok) cnt = n_tok;
    int row0 = mt * BM;
    if (row0 >= cnt) return;
    int rows = cnt - row0; if (rows > BM) rows = BM;
    int n0 = nt * BN;

    __shared__ __align__(16) unsigned short As[2][BM][AKP];
    __shared__ __align__(16) unsigned short Bs[2][2][BN * BK];
    __shared__ int tok[BM];

    int t = threadIdx.x;
    for (int i = t; i < BM; i += 512) {
        int tk = (i < rows) ? tlist[e * n_tok + row0 + i] : -1;
        tok[i] = (tk >= 0 && tk < n_tok) ? tk : -1;
    }
    __syncthreads();

    int wid = t >> 6, lane = t & 63;
    int ar = t >> 2, ah = (t & 3) * 8;
    int atok = tok[ar];
    const float* aptr = x + (size_t)(atok < 0 ? 0 : atok) * HDIM + ah;

    const unsigned short* gub = gu + (size_t)((e * 2) * NT + nt) * NKT * 1024;
    // fallback (direct) coords: 2mat*32n*8kq = 512 threads
    int fb_mat = t >> 8, fb_n = (t >> 3) & 31, fb_k = (t & 7) * 4;
    const float* wdir = (fb_mat ? Wu : Wg) + (size_t)e * HDIM * IDIM + n0 + fb_n;

    f32x4 Ar[2];
    float Bf[4];

    auto loadA = [&](int kt) {
        Ar[0] = *(const f32x4*)(aptr + kt * BK);
        Ar[1] = *(const f32x4*)(aptr + kt * BK + 4);
    };
    auto storeA = [&](int buf) {
        short8v s;
        s[0] = f2bf(Ar[0][0]); s[1] = f2bf(Ar[0][1]); s[2] = f2bf(Ar[0][2]); s[3] = f2bf(Ar[0][3]);
        s[4] = f2bf(Ar[1][0]); s[5] = f2bf(Ar[1][1]); s[6] = f2bf(Ar[1][2]); s[7] = f2bf(Ar[1][3]);
        *(short8v*)&As[buf][ar][ah] = s;
    };
    auto stageB = [&](int kt, int buf) {
        if (wid < 4) {
            int mat = wid >> 1, seg = wid & 1;
            const unsigned short* s = gub + (size_t)mat * (NT * NKT * 1024)
                                    + (size_t)kt * 1024 + seg * 512 + lane * 8;
            gll16(s, &Bs[buf][mat][seg * 512]);
        }
    };
    auto loadB_dir = [&](int kt) {
        #pragma unroll
        for (int j = 0; j < 4; ++j)
            Bf[j] = wdir[(size_t)(kt * BK + fb_k + j) * IDIM];
    };
    auto storeB_dir = [&](int buf) {
        ushort4 b;
        b.x = f2bf(Bf[0]); b.y = f2bf(Bf[1]); b.z = f2bf(Bf[2]); b.w = f2bf(Bf[3]);
        int idx = (fb_n * 32 + fb_k) ^ ((fb_n & 7) << 3);
        *(ushort4*)&Bs[buf][fb_mat][idx] = b;
    };

    int wm = wid >> 1, wn = wid & 1;
    int lr = lane & 15, lk = lane >> 4, lk8 = lk * 8;
    int nB = wn * 16 + lr;
    int idxB = (nB * 32 + lk8) ^ ((nB & 7) << 3);
    f32x4 acc[2][2] = {};

    loadA(0);
    if (PACKED) stageB(0, 0); else loadB_dir(0);
    storeA(0);
    if (!PACKED) storeB_dir(0);
    __syncthreads();

    for (int kt = 0; kt < NKT; ++kt) {
        int cur = kt & 1, nxt = cur ^ 1;
        if (kt + 1 < NKT) {
            loadA(kt + 1);
            if (PACKED) stageB(kt + 1, nxt); else loadB_dir(kt + 1);
        }
        bf16x8 a0 = *(const bf16x8*)&As[cur][wm * 32 + lr][lk8];
        bf16x8 a1 = *(const bf16x8*)&As[cur][wm * 32 + 16 + lr][lk8];
        bf16x8 b0 = *(const bf16x8*)&Bs[cur][0][idxB];
        bf16x8 b1 = *(const bf16x8*)&Bs[cur][1][idxB];
        acc[0][0] = __builtin_amdgcn_mfma_f32_16x16x32_bf16(a0, b0, acc[0][0], 0, 0, 0);
        acc[1][0] = __builtin_amdgcn_mfma_f32_16x16x32_bf16(a1, b0, acc[1][0], 0, 0, 0);
        acc[0][1] = __builtin_amdgcn_mfma_f32_16x16x32_bf16(a0, b1, acc[0][1], 0, 0, 0);
        acc[1][1] = __builtin_amdgcn_mfma_f32_16x16x32_bf16(a1, b1, acc[1][1], 0, 0, 0);
        if (kt + 1 < NKT) {
            storeA(nxt);
            if (!PACKED) storeB_dir(nxt);
        }
        __syncthreads();
    }

    #pragma unroll
    for (int fm = 0; fm < 2; ++fm) {
        #pragma unroll
        for (int rr = 0; rr < 4; ++rr) {
            int row = wm * 32 + fm * 16 + lk * 4 + rr;
            if (row < rows) {
                int tk = tok[row];
                if (tk >= 0) {
                    float g = acc[fm][0][rr];
                    float u = acc[fm][1][rr];
                    float s = g / (1.0f + __expf(-g)) * u;
                    inter[(size_t)tk * IDIM + n0 + wn * 16 + lr] = f2bf(s);
                }
            }
        }
    }
}

// ---------------- phase 2: out = inter @ down^T (k contiguous in Wd -> direct staging) ----------------
__global__ __launch_bounds__(512) void down_kernel(
    const unsigned short* __restrict__ inter, const float* __restrict__ Wd,
    const int* __restrict__ counts, const int* __restrict__ tlist,
    float* __restrict__ out, int n_tok)
{
    int bid = blockIdx.x;
    int e = bid / (MT_MAX * NT);
    int rem = bid % (MT_MAX * NT);
    int mt = rem / NT, jt = rem % NT;
    int cnt = counts[e];
    if (cnt < 0) cnt = 0;
    if (cnt > n_tok) cnt = n_tok;
    int row0 = mt * BM;
    if (row0 >= cnt) return;
    int rows = cnt - row0; if (rows > BM) rows = BM;
    int j0 = jt * BN;

    __shared__ __align__(16) unsigned short As[2][BM][AKP];
    __shared__ __align__(16) unsigned short Bs[2][BN][AKP];
    __shared__ int tok[BM];

    int t = threadIdx.x;
    for (int i = t; i < BM; i += 512) {
        int tk = (i < rows) ? tlist[e * n_tok + row0 + i] : -1;
        tok[i] = (tk >= 0 && tk < n_tok) ? tk : -1;
    }
    __syncthreads();

    int wid = t >> 6, lane = t & 63;
    int ar = t >> 2, ah = (t & 3) * 8;
    int atok = tok[ar];
    const unsigned short* iptr = inter + (size_t)(atok < 0 ? 0 : atok) * IDIM + ah;
    // B: threads 0..255, j = t>>3, kq = (t&7)*4
    int bj = t >> 3, bk = (t & 7) * 4;
    const float* wdb = Wd + (size_t)e * IDIM * HDIM + (size_t)(j0 + bj) * HDIM + bk;

    uint4 Areg;
    float4 Breg;

    auto loadA = [&](int kt) { Areg = *(const uint4*)(iptr + kt * BK); };
    auto storeA = [&](int buf) { *(uint4*)&As[buf][ar][ah] = Areg; };
    auto loadB = [&](int kt) { if (t < 256) Breg = *(const float4*)(wdb + kt * BK); };
    auto storeB = [&](int buf) {
        if (t < 256) {
            ushort4 b;
            b.x = f2bf(Breg.x); b.y = f2bf(Breg.y); b.z = f2bf(Breg.z); b.w = f2bf(Breg.w);
            *(ushort4*)&Bs[buf][bj][bk] = b;
        }
    };

    int wm = wid >> 1, wn = wid & 1;
    int lr = lane & 15, lk = lane >> 4, lk8 = lk * 8;
    f32x4 acc[2] = {};

    loadA(0); loadB(0);
    storeA(0); storeB(0);
    __syncthreads();

    for (int kt = 0; kt < NKT; ++kt) {
        int cur = kt & 1, nxt = cur ^ 1;
        if (kt + 1 < NKT) { loadA(kt + 1); loadB(kt + 1); }
        bf16x8 a0 = *(const bf16x8*)&As[cur][wm * 32 + lr][lk8];
        bf16x8 a1 = *(const bf16x8*)&As[cur][wm * 32 + 16 + lr][lk8];
        bf16x8 bv = *(const bf16x8*)&Bs[cur][wn * 16 + lr][lk8];
        acc[0] = __builtin_amdgcn_mfma_f32_16x16x32_bf16(a0, bv, acc[0], 0, 0, 0);
        acc[1] = __builtin_amdgcn_mfma_f32_16x16x32_bf16(a1, bv, acc[1], 0, 0, 0);
        if (kt + 1 < NKT) { storeA(nxt); storeB(nxt); }
        __syncthreads();
    }

    #pragma unroll
    for (int fm = 0; fm < 2; ++fm) {
        #pragma unroll
        for (int rr = 0; rr < 4; ++rr) {
            int row = wm * 32 + fm * 16 + lk * 4 + rr;
            if (row < rows) {
                int tk = tok[row];
                if (tk >= 0)
                    out[(size_t)tk * HDIM + j0 + wn * 16 + lr] = acc[fm][rr];
            }
        }
    }
}

extern "C" void kernel_launch(void* const* d_in, const int* in_sizes, int n_in,
                              void* d_out, int out_size, void* d_ws, size_t ws_size,
                              hipStream_t stream) {
    const float* x  = (const float*)d_in[0];
    const int* eidx = (const int*)d_in[1];
    const float* Wg = (const float*)d_in[2];
    const float* Wu = (const float*)d_in[3];
    const float* Wd = (const float*)d_in[4];
    float* out = (float*)d_out;
    int n_tok = in_sizes[1];   // B*S = 2048

    char* ws = (char*)d_ws;
    size_t off_tlist = 1024;
    size_t off_inter = (size_t)1 << 18;                              // 256 KB
    size_t off_gu    = off_inter + (size_t)n_tok * IDIM * 2;         // + 4 MB
    size_t sz_gu     = (size_t)E_NUM * 2 * NT * NKT * 2048;          // 64 MB

    int* counts           = (int*)ws;
    int* tlist            = (int*)(ws + off_tlist);
    unsigned short* inter = (unsigned short*)(ws + off_inter);
    unsigned short* gu    = (unsigned short*)(ws + off_gu);

    bool packGU = ws_size >= off_gu + sz_gu;

    route_kernel<<<1, 256, 0, stream>>>(eidx, n_tok, counts, tlist);
    if (packGU) pack_gu_kernel<<<E_NUM * 2 * 32 * 4, 256, 0, stream>>>(Wg, Wu, gu);

    int grid = E_NUM * MT_MAX * NT;
    if (packGU)
        gateup_kernel<1><<<grid, 512, 0, stream>>>(x, Wg, Wu, gu, counts, tlist, inter, n_tok);
    else
        gateup_kernel<0><<<grid, 512, 0, stream>>>(x, Wg, Wu, gu, counts, tlist, inter, n_tok);
    down_kernel<<<grid, 512, 0, stream>>>(inter, Wd, counts, tlist, out, n_tok);
}